// Round 1
// baseline (542.812 us; speedup 1.0000x reference)
//
#include <hip/hip_runtime.h>
#include <math.h>

#define DD 128
#define COUT 40
#define BN_EPS 1e-5f
#define L2_EPS 1e-12f

typedef __attribute__((ext_vector_type(8))) short bf16x8;
typedef __attribute__((ext_vector_type(4))) float f32x4;

static __device__ inline unsigned short f2bf(float f) {
    unsigned int x = __float_as_uint(f);
    unsigned int r = (x + 0x7FFFu + ((x >> 16) & 1u)) >> 16;   // RNE
    return (unsigned short)r;
}
static __device__ inline float bf2f(unsigned short u) {
    return __uint_as_float(((unsigned int)u) << 16);
}

// ---------------- setup kernels ----------------

// deg[] is memset to 0 before this. pord[i] = rank of edge i within its dst bucket.
__global__ void k_hist(const int* __restrict__ ei, int E, int* __restrict__ deg,
                       int* __restrict__ pord) {
    int i = blockIdx.x * blockDim.x + threadIdx.x;
    if (i < E) pord[i] = atomicAdd(&deg[ei[E + i]], 1);
}

// exclusive scan over n+1 entries of (deg[i]+1), 3 phases; also computes dinv.
__global__ void k_scan_a(const int* __restrict__ deg, int* __restrict__ row_ptr,
                         int* __restrict__ bsum, float* __restrict__ dinv, int n) {
    __shared__ int s[256];
    int t = threadIdx.x;
    int idx = blockIdx.x * 256 + t;
    int v = (idx < n) ? deg[idx] + 1 : 0;      // +1 = self loop
    if (idx < n) dinv[idx] = rsqrtf((float)v);
    s[t] = v; __syncthreads();
    for (int off = 1; off < 256; off <<= 1) {
        int x = (t >= off) ? s[t - off] : 0;
        __syncthreads(); s[t] += x; __syncthreads();
    }
    if (idx <= n) row_ptr[idx] = s[t] - v;     // local exclusive
    if (t == 255) bsum[blockIdx.x] = s[255];
}

__global__ void k_scan_b(const int* __restrict__ bsum, int* __restrict__ boff, int nb) {
    __shared__ int s[512];
    int t = threadIdx.x;
    int v = (t < nb) ? bsum[t] : 0;
    s[t] = v; __syncthreads();
    for (int off = 1; off < 512; off <<= 1) {
        int x = (t >= off) ? s[t - off] : 0;
        __syncthreads(); s[t] += x; __syncthreads();
    }
    if (t < nb) boff[t] = s[t] - v;            // exclusive block offsets
}

__global__ void k_scan_c(int* __restrict__ row_ptr, const int* __restrict__ boff, int n1) {
    int idx = blockIdx.x * blockDim.x + threadIdx.x;
    if (idx < n1) row_ptr[idx] += boff[idx >> 8];
}

// pure scatter store, no atomics: epair[pos] = {src, bits(dinv[src])}
// edges go to row_ptr[v] + pord[i]; self loop goes to row_ptr[v+1]-1.
__global__ void k_fill(const int* __restrict__ ei, const int* __restrict__ pord,
                       int E, int n, const int* __restrict__ row_ptr,
                       const float* __restrict__ dinv, int2* __restrict__ epair) {
    int i = blockIdx.x * blockDim.x + threadIdx.x;
    int total = E + n;
    if (i >= total) return;
    int u, pos;
    if (i < E) {
        u = ei[i];
        int v = ei[E + i];
        pos = row_ptr[v] + pord[i];
    } else {
        u = i - E;                              // self loop
        pos = row_ptr[u + 1] - 1;
    }
    int2 pr; pr.x = u; pr.y = __float_as_int(dinv[u]);
    epair[pos] = pr;
}

// One dispatch: repack W1/W2/W3 (blocks 0..23), Wout (24..26), zero stats (27).
__global__ void k_wrepack_all(const float* __restrict__ W1, const float* __restrict__ W2,
                              const float* __restrict__ W3, const float* __restrict__ Wout,
                              unsigned short* __restrict__ wb,    // 3 * 16384
                              unsigned short* __restrict__ wob,   // 6144
                              float* __restrict__ stats) {        // 768
    int b = blockIdx.x;
    if (b < 24) {
        int wi = b >> 3;
        const float* W = (wi == 0) ? W1 : (wi == 1) ? W2 : W3;
        unsigned short* out = wb + wi * 16384;
        int idx = (b & 7) * 256 + threadIdx.x;      // 0..2047
        int kc = idx >> 9;
        int cc = (idx >> 6) & 7;
        int lane = idx & 63;
        int n = cc * 16 + (lane & 15);
        int kb = kc * 32 + (lane >> 4) * 8;
        unsigned short tmp[8];
#pragma unroll
        for (int j = 0; j < 8; j++) tmp[j] = f2bf(W[(size_t)(kb + j) * DD + n]);
        *(uint4*)&out[(size_t)idx * 8] = *(const uint4*)tmp;
    } else if (b < 27) {
        int idx = (b - 24) * 256 + threadIdx.x;     // 0..767
        int kc = idx / 192;
        int rem = idx % 192;
        int cc = rem >> 6;
        int lane = rem & 63;
        int n = cc * 16 + (lane & 15);
        int kb = kc * 32 + (lane >> 4) * 8;
        unsigned short tmp[8];
#pragma unroll
        for (int j = 0; j < 8; j++)
            tmp[j] = (n < COUT) ? f2bf(Wout[(size_t)(kb + j) * COUT + n]) : 0;
        *(uint4*)&wob[(size_t)idx * 8] = *(const uint4*)tmp;
    } else {
        stats[threadIdx.x] = 0.f;
        stats[256 + threadIdx.x] = 0.f;
        stats[512 + threadIdx.x] = 0.f;
    }
}

// ---------------- compute kernels ----------------

// linb(bf16) = x(fp32) @ W1 via MFMA. Block = 4 waves, 64 rows. Layer-1 only.
__global__ __launch_bounds__(256) void k_gemm0(const float* __restrict__ A,
                                               const unsigned short* __restrict__ Wb,
                                               unsigned short* __restrict__ C, int nrows) {
    __shared__ __align__(16) unsigned short Ws[16384];   // 32 KB
    const int tid = threadIdx.x;
    for (int i = tid; i < 2048; i += 256)
        ((uint4*)Ws)[i] = ((const uint4*)Wb)[i];
    __syncthreads();

    const int wv = tid >> 6;
    const int lane = tid & 63;
    const int R0 = blockIdx.x * 64 + wv * 16;
    if (R0 >= nrows) return;
    const int m = lane & 15, q = lane >> 4;
    int rr = R0 + m; if (rr >= nrows) rr = nrows - 1;
    const float* Ar = A + (size_t)rr * DD + q * 8;

    bf16x8 af[4];
#pragma unroll
    for (int kc = 0; kc < 4; kc++) {
        float4 lo = *(const float4*)(Ar + kc * 32);
        float4 hi = *(const float4*)(Ar + kc * 32 + 4);
        unsigned short t[8];
        t[0] = f2bf(lo.x); t[1] = f2bf(lo.y); t[2] = f2bf(lo.z); t[3] = f2bf(lo.w);
        t[4] = f2bf(hi.x); t[5] = f2bf(hi.y); t[6] = f2bf(hi.z); t[7] = f2bf(hi.w);
        af[kc] = *(const bf16x8*)t;
    }

    f32x4 acc[8];
#pragma unroll
    for (int cc = 0; cc < 8; cc++) acc[cc] = (f32x4){0.f, 0.f, 0.f, 0.f};
#pragma unroll
    for (int kc = 0; kc < 4; kc++)
#pragma unroll
        for (int cc = 0; cc < 8; cc++) {
            bf16x8 b = *(const bf16x8*)&Ws[(size_t)((kc * 8 + cc) * 64 + lane) * 8];
            acc[cc] = __builtin_amdgcn_mfma_f32_16x16x32_bf16(af[kc], b, acc[cc], 0, 0, 0);
        }

#pragma unroll
    for (int cc = 0; cc < 8; cc++)
#pragma unroll
        for (int i = 0; i < 4; i++) {
            int r = R0 + q * 4 + i;
            if (r < nrows) C[(size_t)r * DD + cc * 16 + m] = f2bf(acc[cc][i]);
        }
}

// Aggregation + fused BN-stats.
// One wave per node. 16 lanes x 16B cover one 128-col bf16 row -> wave gathers
// 4 rows/load instr; unroll 2 -> 8 edges in flight. Grid-stride over nodes;
// per-wave stats accumulated in registers, block-reduced in LDS, one atomicAdd
// per column per block.
__global__ __launch_bounds__(256) void k_aggs(const unsigned short* __restrict__ lin,
                                              const int* __restrict__ row_ptr,
                                              const int2* __restrict__ epair,
                                              const float* __restrict__ dinv,
                                              const float* __restrict__ bias,
                                              unsigned short* __restrict__ outb,
                                              float* __restrict__ stats, int n) {
    const int tid = threadIdx.x;
    const int wv = tid >> 6;
    const int lane = tid & 63;
    const int g = lane >> 4;          // edge slot 0..3
    const int ci = (lane & 15) * 8;   // col base (8 cols per lane)

    float bs[8];
    {
        float4 b0 = *(const float4*)&bias[ci];
        float4 b1 = *(const float4*)&bias[ci + 4];
        bs[0] = b0.x; bs[1] = b0.y; bs[2] = b0.z; bs[3] = b0.w;
        bs[4] = b1.x; bs[5] = b1.y; bs[6] = b1.z; bs[7] = b1.w;
    }

    float s[8], q[8];
#pragma unroll
    for (int k = 0; k < 8; k++) { s[k] = 0.f; q[k] = 0.f; }

    const int wstride = gridDim.x * 4;
    for (int v = blockIdx.x * 4 + wv; v < n; v += wstride) {
        int rp0 = row_ptr[v];
        int deg = row_ptr[v + 1] - rp0;
        float dv = dinv[v];
        float acc[8];
#pragma unroll
        for (int k = 0; k < 8; k++) acc[k] = 0.f;

        for (int j = 0; j < deg; j += 8) {
            int i0 = j + g;
            int i1 = j + 4 + g;
            if (i0 < deg) {
                int2 p = epair[rp0 + i0];
                float w = dv * __int_as_float(p.y);
                uint4 t = *(const uint4*)&lin[(size_t)p.x * DD + ci];
                acc[0] += w * __uint_as_float(t.x << 16);
                acc[1] += w * __uint_as_float(t.x & 0xFFFF0000u);
                acc[2] += w * __uint_as_float(t.y << 16);
                acc[3] += w * __uint_as_float(t.y & 0xFFFF0000u);
                acc[4] += w * __uint_as_float(t.z << 16);
                acc[5] += w * __uint_as_float(t.z & 0xFFFF0000u);
                acc[6] += w * __uint_as_float(t.w << 16);
                acc[7] += w * __uint_as_float(t.w & 0xFFFF0000u);
            }
            if (i1 < deg) {
                int2 p = epair[rp0 + i1];
                float w = dv * __int_as_float(p.y);
                uint4 t = *(const uint4*)&lin[(size_t)p.x * DD + ci];
                acc[0] += w * __uint_as_float(t.x << 16);
                acc[1] += w * __uint_as_float(t.x & 0xFFFF0000u);
                acc[2] += w * __uint_as_float(t.y << 16);
                acc[3] += w * __uint_as_float(t.y & 0xFFFF0000u);
                acc[4] += w * __uint_as_float(t.z << 16);
                acc[5] += w * __uint_as_float(t.z & 0xFFFF0000u);
                acc[6] += w * __uint_as_float(t.w << 16);
                acc[7] += w * __uint_as_float(t.w & 0xFFFF0000u);
            }
        }

        // combine the 4 edge-slot partials: lanes {l, l^16, l^32, l^48}
#pragma unroll
        for (int k = 0; k < 8; k++) {
            acc[k] += __shfl_xor(acc[k], 16, 64);
            acc[k] += __shfl_xor(acc[k], 32, 64);
            acc[k] += bs[k];
        }

        if (g == 0) {
            unsigned short t[8];
#pragma unroll
            for (int k = 0; k < 8; k++) {
                t[k] = f2bf(acc[k]);
                s[k] += acc[k];
                q[k] += acc[k] * acc[k];
            }
            *(uint4*)&outb[(size_t)v * DD + ci] = *(const uint4*)t;
        }
    }

    // block-level stats reduction
    __shared__ float sh[4][128];
    __shared__ float qh[4][128];
    if (g == 0) {
#pragma unroll
        for (int k = 0; k < 8; k++) { sh[wv][ci + k] = s[k]; qh[wv][ci + k] = q[k]; }
    }
    __syncthreads();
    if (tid < 128) {
        float a = sh[0][tid] + sh[1][tid] + sh[2][tid] + sh[3][tid];
        float b = qh[0][tid] + qh[1][tid] + qh[2][tid] + qh[3][tid];
        atomicAdd(&stats[tid], a);
        atomicAdd(&stats[128 + tid], b);
    }
}

// Fused: h = l2norm(relu(bn(aggX)) [+ res]);  hbf_out = bf16(h);  linb_out = h @ W.
template <bool HAS_RES>
__global__ __launch_bounds__(256) void k_fused(const unsigned short* __restrict__ aggX,
                                               const float* __restrict__ stats,
                                               const float* __restrict__ g,
                                               const float* __restrict__ be, float inv_n,
                                               const unsigned short* __restrict__ resb,
                                               const unsigned short* __restrict__ Wb,
                                               unsigned short* __restrict__ hbf_out,
                                               unsigned short* __restrict__ linb_out,
                                               int nrows) {
    __shared__ __align__(16) unsigned short Ws[16384];
    __shared__ float ssl[256];          // scale / shift
    const int tid = threadIdx.x;
    for (int i = tid; i < 2048; i += 256)
        ((uint4*)Ws)[i] = ((const uint4*)Wb)[i];
    if (tid < 128) {
        float mu = stats[tid] * inv_n;
        float var = stats[128 + tid] * inv_n - mu * mu;
        float sc = g[tid] * rsqrtf(var + BN_EPS);
        ssl[tid] = sc;
        ssl[128 + tid] = be[tid] - mu * sc;
    }
    __syncthreads();

    const int wv = tid >> 6;
    const int lane = tid & 63;
    const int R0 = blockIdx.x * 64 + wv * 16;
    if (R0 >= nrows) return;
    const int m = lane & 15, q = lane >> 4;
    int rr = R0 + m; if (rr >= nrows) rr = nrows - 1;
    const unsigned short* Ar = aggX + (size_t)rr * DD + q * 8;
    const unsigned short* Rr = HAS_RES ? resb + (size_t)rr * DD + q * 8 : nullptr;

    float y[4][8];
    float sq = 0.f;
#pragma unroll
    for (int kc = 0; kc < 4; kc++) {
        ushort4 lo = *(const ushort4*)(Ar + kc * 32);
        ushort4 hi = *(const ushort4*)(Ar + kc * 32 + 4);
        unsigned short av[8] = {lo.x, lo.y, lo.z, lo.w, hi.x, hi.y, hi.z, hi.w};
        int c0 = kc * 32 + q * 8;
        float4 sc0 = *(const float4*)&ssl[c0];
        float4 sc1 = *(const float4*)&ssl[c0 + 4];
        float4 sh0 = *(const float4*)&ssl[128 + c0];
        float4 sh1 = *(const float4*)&ssl[128 + c0 + 4];
        float scv[8] = {sc0.x, sc0.y, sc0.z, sc0.w, sc1.x, sc1.y, sc1.z, sc1.w};
        float shv[8] = {sh0.x, sh0.y, sh0.z, sh0.w, sh1.x, sh1.y, sh1.z, sh1.w};
        if (HAS_RES) {
            ushort4 rl = *(const ushort4*)(Rr + kc * 32);
            ushort4 rh = *(const ushort4*)(Rr + kc * 32 + 4);
            unsigned short rv[8] = {rl.x, rl.y, rl.z, rl.w, rh.x, rh.y, rh.z, rh.w};
#pragma unroll
            for (int j = 0; j < 8; j++) {
                float yy = fmaxf(bf2f(av[j]) * scv[j] + shv[j], 0.f) + bf2f(rv[j]);
                y[kc][j] = yy; sq += yy * yy;
            }
        } else {
#pragma unroll
            for (int j = 0; j < 8; j++) {
                float yy = fmaxf(bf2f(av[j]) * scv[j] + shv[j], 0.f);
                y[kc][j] = yy; sq += yy * yy;
            }
        }
    }
    sq += __shfl_xor(sq, 16, 64);
    sq += __shfl_xor(sq, 32, 64);
    float inv = 1.f / fmaxf(sqrtf(sq), L2_EPS);

    bf16x8 af[4];
#pragma unroll
    for (int kc = 0; kc < 4; kc++) {
        unsigned short t[8];
#pragma unroll
        for (int j = 0; j < 8; j++) t[j] = f2bf(y[kc][j] * inv);
        af[kc] = *(const bf16x8*)t;
        *(bf16x8*)&hbf_out[(size_t)rr * DD + q * 8 + kc * 32] = af[kc];
    }

    f32x4 acc[8];
#pragma unroll
    for (int cc = 0; cc < 8; cc++) acc[cc] = (f32x4){0.f, 0.f, 0.f, 0.f};
#pragma unroll
    for (int kc = 0; kc < 4; kc++)
#pragma unroll
        for (int cc = 0; cc < 8; cc++) {
            bf16x8 b = *(const bf16x8*)&Ws[(size_t)((kc * 8 + cc) * 64 + lane) * 8];
            acc[cc] = __builtin_amdgcn_mfma_f32_16x16x32_bf16(af[kc], b, acc[cc], 0, 0, 0);
        }

#pragma unroll
    for (int cc = 0; cc < 8; cc++)
#pragma unroll
        for (int i = 0; i < 4; i++) {
            int r = R0 + q * 4 + i;
            if (r < nrows) linb_out[(size_t)r * DD + cc * 16 + m] = f2bf(acc[cc][i]);
        }
}

// Fused output: h3 = l2norm(relu(bn(aggX)) + res);  out = h3 @ Wout + bout (fp32)
__global__ __launch_bounds__(256) void k_outfused(const unsigned short* __restrict__ aggX,
                                                  const float* __restrict__ stats,
                                                  const float* __restrict__ g,
                                                  const float* __restrict__ be, float inv_n,
                                                  const unsigned short* __restrict__ resb,
                                                  const unsigned short* __restrict__ wob,
                                                  const float* __restrict__ bout,
                                                  float* __restrict__ C, int nrows) {
    __shared__ __align__(16) unsigned short Ws[6144];
    __shared__ float ssl[256];
    const int tid = threadIdx.x;
    for (int i = tid; i < 768; i += 256)
        ((uint4*)Ws)[i] = ((const uint4*)wob)[i];
    if (tid < 128) {
        float mu = stats[tid] * inv_n;
        float var = stats[128 + tid] * inv_n - mu * mu;
        float sc = g[tid] * rsqrtf(var + BN_EPS);
        ssl[tid] = sc;
        ssl[128 + tid] = be[tid] - mu * sc;
    }
    __syncthreads();

    const int wv = tid >> 6;
    const int lane = tid & 63;
    const int R0 = blockIdx.x * 64 + wv * 16;
    if (R0 >= nrows) return;
    const int m = lane & 15, q = lane >> 4;
    int rr = R0 + m; if (rr >= nrows) rr = nrows - 1;
    const unsigned short* Ar = aggX + (size_t)rr * DD + q * 8;
    const unsigned short* Rr = resb + (size_t)rr * DD + q * 8;

    float y[4][8];
    float sq = 0.f;
#pragma unroll
    for (int kc = 0; kc < 4; kc++) {
        ushort4 lo = *(const ushort4*)(Ar + kc * 32);
        ushort4 hi = *(const ushort4*)(Ar + kc * 32 + 4);
        ushort4 rl = *(const ushort4*)(Rr + kc * 32);
        ushort4 rh = *(const ushort4*)(Rr + kc * 32 + 4);
        unsigned short av[8] = {lo.x, lo.y, lo.z, lo.w, hi.x, hi.y, hi.z, hi.w};
        unsigned short rv[8] = {rl.x, rl.y, rl.z, rl.w, rh.x, rh.y, rh.z, rh.w};
        int c0 = kc * 32 + q * 8;
        float4 sc0 = *(const float4*)&ssl[c0];
        float4 sc1 = *(const float4*)&ssl[c0 + 4];
        float4 sh0 = *(const float4*)&ssl[128 + c0];
        float4 sh1 = *(const float4*)&ssl[128 + c0 + 4];
        float scv[8] = {sc0.x, sc0.y, sc0.z, sc0.w, sc1.x, sc1.y, sc1.z, sc1.w};
        float shv[8] = {sh0.x, sh0.y, sh0.z, sh0.w, sh1.x, sh1.y, sh1.z, sh1.w};
#pragma unroll
        for (int j = 0; j < 8; j++) {
            float yy = fmaxf(bf2f(av[j]) * scv[j] + shv[j], 0.f) + bf2f(rv[j]);
            y[kc][j] = yy; sq += yy * yy;
        }
    }
    sq += __shfl_xor(sq, 16, 64);
    sq += __shfl_xor(sq, 32, 64);
    float inv = 1.f / fmaxf(sqrtf(sq), L2_EPS);

    bf16x8 af[4];
#pragma unroll
    for (int kc = 0; kc < 4; kc++) {
        unsigned short t[8];
#pragma unroll
        for (int j = 0; j < 8; j++) t[j] = f2bf(y[kc][j] * inv);
        af[kc] = *(const bf16x8*)t;
    }

    f32x4 acc[3];
#pragma unroll
    for (int cc = 0; cc < 3; cc++) acc[cc] = (f32x4){0.f, 0.f, 0.f, 0.f};
#pragma unroll
    for (int kc = 0; kc < 4; kc++)
#pragma unroll
        for (int cc = 0; cc < 3; cc++) {
            bf16x8 b = *(const bf16x8*)&Ws[(size_t)((kc * 3 + cc) * 64 + lane) * 8];
            acc[cc] = __builtin_amdgcn_mfma_f32_16x16x32_bf16(af[kc], b, acc[cc], 0, 0, 0);
        }

#pragma unroll
    for (int cc = 0; cc < 3; cc++) {
        int col = cc * 16 + m;
        if (col < COUT) {
            float bb = bout[col];
#pragma unroll
            for (int i = 0; i < 4; i++) {
                int r = R0 + q * 4 + i;
                if (r < nrows) C[(size_t)r * COUT + col] = acc[cc][i] + bb;
            }
        }
    }
}

// ---------------- host ----------------

extern "C" void kernel_launch(void* const* d_in, const int* in_sizes, int n_in,
                              void* d_out, int out_size, void* d_ws, size_t ws_size,
                              hipStream_t stream) {
    const float* x    = (const float*)d_in[0];
    const int*   ei   = (const int*)d_in[1];
    const float* W1   = (const float*)d_in[2];
    const float* b1   = (const float*)d_in[3];
    const float* W2   = (const float*)d_in[4];
    const float* b2   = (const float*)d_in[5];
    const float* W3   = (const float*)d_in[6];
    const float* b3   = (const float*)d_in[7];
    const float* g1   = (const float*)d_in[8];
    const float* be1  = (const float*)d_in[9];
    const float* g2   = (const float*)d_in[10];
    const float* be2  = (const float*)d_in[11];
    const float* g3   = (const float*)d_in[12];
    const float* be3  = (const float*)d_in[13];
    const float* Wout = (const float*)d_in[14];
    const float* bout = (const float*)d_in[15];
    float* out = (float*)d_out;

    const int N = in_sizes[0] / DD;
    const int E = in_sizes[1] / 2;
    const int NNZ = E + N;

    // workspace layout
    char* w = (char*)d_ws;
    unsigned short* linb = (unsigned short*)w; w += (size_t)N * DD * sizeof(unsigned short);
    unsigned short* aggA = (unsigned short*)w; w += (size_t)N * DD * sizeof(unsigned short);
    unsigned short* aggB = (unsigned short*)w; w += (size_t)N * DD * sizeof(unsigned short);
    unsigned short* hbf1 = (unsigned short*)w; w += (size_t)N * DD * sizeof(unsigned short);
    unsigned short* hbf2 = (unsigned short*)w; w += (size_t)N * DD * sizeof(unsigned short);
    unsigned short* wb   = (unsigned short*)w; w += 3 * 16384 * sizeof(unsigned short);
    unsigned short* wob  = (unsigned short*)w; w += 6144 * sizeof(unsigned short);
    int2* epair  = (int2*)w;                   w += (size_t)NNZ * sizeof(int2);
    int* pord    = (int*)w;                    w += (size_t)E * sizeof(int);
    int* deg     = (int*)w;                    w += (size_t)N * sizeof(int);
    int* row_ptr = (int*)w;                    w += (size_t)(N + 1) * sizeof(int);
    float* dinv  = (float*)w;                  w += (size_t)N * sizeof(float);
    int* bsum    = (int*)w;                    w += 512 * sizeof(int);
    int* boff    = (int*)w;                    w += 512 * sizeof(int);
    float* stats = (float*)w;                  w += 768 * sizeof(float);

    const int NB = (N + 1 + 255) / 256;      // scan blocks

    // ---- CSR build + weight repack ----
    hipMemsetAsync(deg, 0, (size_t)N * sizeof(int), stream);
    k_wrepack_all<<<28, 256, 0, stream>>>(W1, W2, W3, Wout, wb, wob, stats);
    k_hist<<<(E + 255) / 256, 256, 0, stream>>>(ei, E, deg, pord);
    k_scan_a<<<NB, 256, 0, stream>>>(deg, row_ptr, bsum, dinv, N);
    k_scan_b<<<1, 512, 0, stream>>>(bsum, boff, NB);
    k_scan_c<<<(N + 1 + 255) / 256, 256, 0, stream>>>(row_ptr, boff, N + 1);
    k_fill<<<(NNZ + 255) / 256, 256, 0, stream>>>(ei, pord, E, N, row_ptr, dinv, epair);

    int gemmGrid = (N + 63) / 64;
    int aggGrid = 2048;                      // 8192 waves, grid-stride over nodes
    float inv_n = 1.0f / (float)N;

    // ---- layer 1 ----
    k_gemm0<<<gemmGrid, 256, 0, stream>>>(x, wb, linb, N);
    k_aggs<<<aggGrid, 256, 0, stream>>>(linb, row_ptr, epair, dinv, b1, aggA, stats, N);
    // ---- layer 2 (post1 fused into gemm2) ----
    k_fused<false><<<gemmGrid, 256, 0, stream>>>(aggA, stats, g1, be1, inv_n,
                                                 nullptr, wb + 16384, hbf1, linb, N);
    k_aggs<<<aggGrid, 256, 0, stream>>>(linb, row_ptr, epair, dinv, b2, aggB, stats + 256, N);
    // ---- layer 3 (post2 fused into gemm3) ----
    k_fused<true><<<gemmGrid, 256, 0, stream>>>(aggB, stats + 256, g2, be2, inv_n,
                                                hbf1, wb + 32768, hbf2, linb, N);
    k_aggs<<<aggGrid, 256, 0, stream>>>(linb, row_ptr, epair, dinv, b3, aggA, stats + 512, N);
    // ---- output (post3 fused into output GEMM) ----
    k_outfused<<<gemmGrid, 256, 0, stream>>>(aggA, stats + 512, g3, be3, inv_n,
                                             hbf2, wob, bout, out, N);
}

// Round 2
// 391.506 us; speedup vs baseline: 1.3865x; 1.3865x over previous
//
#include <hip/hip_runtime.h>
#include <math.h>

#define DD 128
#define COUT 40
#define BN_EPS 1e-5f
#define L2_EPS 1e-12f
#define NREP 64            // stats replicas (atomic-contention spreading)

typedef __attribute__((ext_vector_type(8))) short bf16x8;
typedef __attribute__((ext_vector_type(4))) float f32x4;

static __device__ inline unsigned short f2bf(float f) {
    unsigned int x = __float_as_uint(f);
    unsigned int r = (x + 0x7FFFu + ((x >> 16) & 1u)) >> 16;   // RNE
    return (unsigned short)r;
}
static __device__ inline float bf2f(unsigned short u) {
    return __uint_as_float(((unsigned int)u) << 16);
}

// ---------------- setup kernels ----------------

// deg[] is memset to 0 before this. pord[i] = rank of edge i within its dst bucket.
__global__ void k_hist(const int* __restrict__ ei, int E, int* __restrict__ deg,
                       int* __restrict__ pord) {
    int i = blockIdx.x * blockDim.x + threadIdx.x;
    if (i < E) pord[i] = atomicAdd(&deg[ei[E + i]], 1);
}

// exclusive scan over n+1 entries of (deg[i]+1), 3 phases; also computes dinv.
__global__ void k_scan_a(const int* __restrict__ deg, int* __restrict__ row_ptr,
                         int* __restrict__ bsum, float* __restrict__ dinv, int n) {
    __shared__ int s[256];
    int t = threadIdx.x;
    int idx = blockIdx.x * 256 + t;
    int v = (idx < n) ? deg[idx] + 1 : 0;      // +1 = self loop
    if (idx < n) dinv[idx] = rsqrtf((float)v);
    s[t] = v; __syncthreads();
    for (int off = 1; off < 256; off <<= 1) {
        int x = (t >= off) ? s[t - off] : 0;
        __syncthreads(); s[t] += x; __syncthreads();
    }
    if (idx <= n) row_ptr[idx] = s[t] - v;     // local exclusive
    if (t == 255) bsum[blockIdx.x] = s[255];
}

__global__ void k_scan_b(const int* __restrict__ bsum, int* __restrict__ boff, int nb) {
    __shared__ int s[512];
    int t = threadIdx.x;
    int v = (t < nb) ? bsum[t] : 0;
    s[t] = v; __syncthreads();
    for (int off = 1; off < 512; off <<= 1) {
        int x = (t >= off) ? s[t - off] : 0;
        __syncthreads(); s[t] += x; __syncthreads();
    }
    if (t < nb) boff[t] = s[t] - v;            // exclusive block offsets
}

__global__ void k_scan_c(int* __restrict__ row_ptr, const int* __restrict__ boff, int n1) {
    int idx = blockIdx.x * blockDim.x + threadIdx.x;
    if (idx < n1) row_ptr[idx] += boff[idx >> 8];
}

// pure scatter store, no atomics: epair[pos] = {src, bits(dinv[src])}
// edges go to row_ptr[v] + pord[i]; self loop goes to row_ptr[v+1]-1.
__global__ void k_fill(const int* __restrict__ ei, const int* __restrict__ pord,
                       int E, int n, const int* __restrict__ row_ptr,
                       const float* __restrict__ dinv, int2* __restrict__ epair) {
    int i = blockIdx.x * blockDim.x + threadIdx.x;
    int total = E + n;
    if (i >= total) return;
    int u, pos;
    if (i < E) {
        u = ei[i];
        int v = ei[E + i];
        pos = row_ptr[v] + pord[i];
    } else {
        u = i - E;                              // self loop
        pos = row_ptr[u + 1] - 1;
    }
    int2 pr; pr.x = u; pr.y = __float_as_int(dinv[u]);
    epair[pos] = pr;
}

// One dispatch: repack W1/W2/W3 (blocks 0..23), Wout (24..26), zero stats (27..34).
__global__ void k_wrepack_all(const float* __restrict__ W1, const float* __restrict__ W2,
                              const float* __restrict__ W3, const float* __restrict__ Wout,
                              unsigned short* __restrict__ wb,    // 3 * 16384
                              unsigned short* __restrict__ wob,   // 6144
                              float* __restrict__ stats) {        // 3 * NREP * 256
    int b = blockIdx.x;
    if (b < 24) {
        int wi = b >> 3;
        const float* W = (wi == 0) ? W1 : (wi == 1) ? W2 : W3;
        unsigned short* out = wb + wi * 16384;
        int idx = (b & 7) * 256 + threadIdx.x;      // 0..2047
        int kc = idx >> 9;
        int cc = (idx >> 6) & 7;
        int lane = idx & 63;
        int n = cc * 16 + (lane & 15);
        int kb = kc * 32 + (lane >> 4) * 8;
        unsigned short tmp[8];
#pragma unroll
        for (int j = 0; j < 8; j++) tmp[j] = f2bf(W[(size_t)(kb + j) * DD + n]);
        *(uint4*)&out[(size_t)idx * 8] = *(const uint4*)tmp;
    } else if (b < 27) {
        int idx = (b - 24) * 256 + threadIdx.x;     // 0..767
        int kc = idx / 192;
        int rem = idx % 192;
        int cc = rem >> 6;
        int lane = rem & 63;
        int n = cc * 16 + (lane & 15);
        int kb = kc * 32 + (lane >> 4) * 8;
        unsigned short tmp[8];
#pragma unroll
        for (int j = 0; j < 8; j++)
            tmp[j] = (n < COUT) ? f2bf(Wout[(size_t)(kb + j) * COUT + n]) : 0;
        *(uint4*)&wob[(size_t)idx * 8] = *(const uint4*)tmp;
    } else {
        // zero 3 * NREP * 256 floats = 3*NREP*64 float4s, 8 blocks
        float4 z = make_float4(0.f, 0.f, 0.f, 0.f);
        int idx = (b - 27) * 256 + threadIdx.x;
        for (int i = idx; i < 3 * NREP * 64; i += 8 * 256)
            ((float4*)stats)[i] = z;
    }
}

// ---------------- compute kernels ----------------

// linb(bf16) = x(fp32) @ W1 via MFMA. Block = 4 waves, 64 rows. Layer-1 only.
__global__ __launch_bounds__(256) void k_gemm0(const float* __restrict__ A,
                                               const unsigned short* __restrict__ Wb,
                                               unsigned short* __restrict__ C, int nrows) {
    __shared__ __align__(16) unsigned short Ws[16384];   // 32 KB
    const int tid = threadIdx.x;
    for (int i = tid; i < 2048; i += 256)
        ((uint4*)Ws)[i] = ((const uint4*)Wb)[i];
    __syncthreads();

    const int wv = tid >> 6;
    const int lane = tid & 63;
    const int R0 = blockIdx.x * 64 + wv * 16;
    if (R0 >= nrows) return;
    const int m = lane & 15, q = lane >> 4;
    int rr = R0 + m; if (rr >= nrows) rr = nrows - 1;
    const float* Ar = A + (size_t)rr * DD + q * 8;

    bf16x8 af[4];
#pragma unroll
    for (int kc = 0; kc < 4; kc++) {
        float4 lo = *(const float4*)(Ar + kc * 32);
        float4 hi = *(const float4*)(Ar + kc * 32 + 4);
        unsigned short t[8];
        t[0] = f2bf(lo.x); t[1] = f2bf(lo.y); t[2] = f2bf(lo.z); t[3] = f2bf(lo.w);
        t[4] = f2bf(hi.x); t[5] = f2bf(hi.y); t[6] = f2bf(hi.z); t[7] = f2bf(hi.w);
        af[kc] = *(const bf16x8*)t;
    }

    f32x4 acc[8];
#pragma unroll
    for (int cc = 0; cc < 8; cc++) acc[cc] = (f32x4){0.f, 0.f, 0.f, 0.f};
#pragma unroll
    for (int kc = 0; kc < 4; kc++)
#pragma unroll
        for (int cc = 0; cc < 8; cc++) {
            bf16x8 b = *(const bf16x8*)&Ws[(size_t)((kc * 8 + cc) * 64 + lane) * 8];
            acc[cc] = __builtin_amdgcn_mfma_f32_16x16x32_bf16(af[kc], b, acc[cc], 0, 0, 0);
        }

#pragma unroll
    for (int cc = 0; cc < 8; cc++)
#pragma unroll
        for (int i = 0; i < 4; i++) {
            int r = R0 + q * 4 + i;
            if (r < nrows) C[(size_t)r * DD + cc * 16 + m] = f2bf(acc[cc][i]);
        }
}

// Aggregation + fused BN-stats. One node per HALF-WAVE (max parallelism, no
// grid-stride). Within a half: 2 edge slots x 16 lanes x 16B (uint4) -> each
// load instr gathers 4 rows wave-wide; unroll 2 -> 4 edges in flight per node.
// Stats: per-block LDS reduce, then atomicAdd into one of NREP replicas.
__global__ __launch_bounds__(256) void k_aggs(const unsigned short* __restrict__ lin,
                                              const int* __restrict__ row_ptr,
                                              const int2* __restrict__ epair,
                                              const float* __restrict__ dinv,
                                              const float* __restrict__ bias,
                                              unsigned short* __restrict__ outb,
                                              float* __restrict__ stats, int n) {
    const int tid = threadIdx.x;
    const int wv = tid >> 6;
    const int lane = tid & 63;
    const int half = lane >> 5;
    const int li = lane & 31;
    const int slot = li >> 4;         // 0 / 1
    const int ci = (li & 15) * 8;     // col base, 8 cols per lane

    const int v = blockIdx.x * 8 + wv * 2 + half;
    const bool valid = v < n;

    float acc[8];
#pragma unroll
    for (int k = 0; k < 8; k++) acc[k] = 0.f;

    if (valid) {
        const int s0 = row_ptr[v];
        const int e0 = row_ptr[v + 1];
        const float dv = dinv[v];
        for (int j = s0; j < e0; j += 4) {
            int i0 = j + slot;
            int i1 = j + 2 + slot;
            bool b0 = i0 < e0;
            bool b1 = i1 < e0;
            int2 p0, p1;
            if (b0) p0 = epair[i0];
            if (b1) p1 = epair[i1];
            if (b0) {
                float w = dv * __int_as_float(p0.y);
                uint4 t = *(const uint4*)&lin[(size_t)p0.x * DD + ci];
                acc[0] += w * __uint_as_float(t.x << 16);
                acc[1] += w * __uint_as_float(t.x & 0xFFFF0000u);
                acc[2] += w * __uint_as_float(t.y << 16);
                acc[3] += w * __uint_as_float(t.y & 0xFFFF0000u);
                acc[4] += w * __uint_as_float(t.z << 16);
                acc[5] += w * __uint_as_float(t.z & 0xFFFF0000u);
                acc[6] += w * __uint_as_float(t.w << 16);
                acc[7] += w * __uint_as_float(t.w & 0xFFFF0000u);
            }
            if (b1) {
                float w = dv * __int_as_float(p1.y);
                uint4 t = *(const uint4*)&lin[(size_t)p1.x * DD + ci];
                acc[0] += w * __uint_as_float(t.x << 16);
                acc[1] += w * __uint_as_float(t.x & 0xFFFF0000u);
                acc[2] += w * __uint_as_float(t.y << 16);
                acc[3] += w * __uint_as_float(t.y & 0xFFFF0000u);
                acc[4] += w * __uint_as_float(t.z << 16);
                acc[5] += w * __uint_as_float(t.z & 0xFFFF0000u);
                acc[6] += w * __uint_as_float(t.w << 16);
                acc[7] += w * __uint_as_float(t.w & 0xFFFF0000u);
            }
        }
    }
    // combine the 2 slot partials (lanes l <-> l^16 within each half)
#pragma unroll
    for (int k = 0; k < 8; k++) acc[k] += __shfl_xor(acc[k], 16, 64);

    __shared__ float sh[8][128];
    __shared__ float qh[8][128];
    const int prow = wv * 2 + half;
    if (slot == 0) {
        if (valid) {
            float4 bb0 = *(const float4*)&bias[ci];
            float4 bb1 = *(const float4*)&bias[ci + 4];
            float bs[8] = {bb0.x, bb0.y, bb0.z, bb0.w, bb1.x, bb1.y, bb1.z, bb1.w};
            unsigned short t[8];
#pragma unroll
            for (int k = 0; k < 8; k++) {
                float a = acc[k] + bs[k];
                t[k] = f2bf(a);
                sh[prow][ci + k] = a;
                qh[prow][ci + k] = a * a;
            }
            *(uint4*)&outb[(size_t)v * DD + ci] = *(const uint4*)t;
        } else {
#pragma unroll
            for (int k = 0; k < 8; k++) { sh[prow][ci + k] = 0.f; qh[prow][ci + k] = 0.f; }
        }
    }
    __syncthreads();
    if (tid < 128) {
        float a = 0.f, b = 0.f;
#pragma unroll
        for (int g = 0; g < 8; g++) { a += sh[g][tid]; b += qh[g][tid]; }
        float* st = stats + (size_t)(blockIdx.x & (NREP - 1)) * 256;
        atomicAdd(&st[tid], a);
        atomicAdd(&st[128 + tid], b);
    }
}

// Fused: h = l2norm(relu(bn(aggX)) [+ res]);  hbf_out = bf16(h);  linb_out = h @ W.
template <bool HAS_RES>
__global__ __launch_bounds__(256) void k_fused(const unsigned short* __restrict__ aggX,
                                               const float* __restrict__ stats,
                                               const float* __restrict__ g,
                                               const float* __restrict__ be, float inv_n,
                                               const unsigned short* __restrict__ resb,
                                               const unsigned short* __restrict__ Wb,
                                               unsigned short* __restrict__ hbf_out,
                                               unsigned short* __restrict__ linb_out,
                                               int nrows) {
    __shared__ __align__(16) unsigned short Ws[16384];
    __shared__ float ssl[256];          // scale / shift
    const int tid = threadIdx.x;
    for (int i = tid; i < 2048; i += 256)
        ((uint4*)Ws)[i] = ((const uint4*)Wb)[i];
    if (tid < 128) {
        float sa = 0.f, sb = 0.f;
        for (int r = 0; r < NREP; r++) {
            sa += stats[r * 256 + tid];
            sb += stats[r * 256 + 128 + tid];
        }
        float mu = sa * inv_n;
        float var = sb * inv_n - mu * mu;
        float sc = g[tid] * rsqrtf(var + BN_EPS);
        ssl[tid] = sc;
        ssl[128 + tid] = be[tid] - mu * sc;
    }
    __syncthreads();

    const int wv = tid >> 6;
    const int lane = tid & 63;
    const int R0 = blockIdx.x * 64 + wv * 16;
    if (R0 >= nrows) return;
    const int m = lane & 15, q = lane >> 4;
    int rr = R0 + m; if (rr >= nrows) rr = nrows - 1;
    const unsigned short* Ar = aggX + (size_t)rr * DD + q * 8;
    const unsigned short* Rr = HAS_RES ? resb + (size_t)rr * DD + q * 8 : nullptr;

    float y[4][8];
    float sq = 0.f;
#pragma unroll
    for (int kc = 0; kc < 4; kc++) {
        ushort4 lo = *(const ushort4*)(Ar + kc * 32);
        ushort4 hi = *(const ushort4*)(Ar + kc * 32 + 4);
        unsigned short av[8] = {lo.x, lo.y, lo.z, lo.w, hi.x, hi.y, hi.z, hi.w};
        int c0 = kc * 32 + q * 8;
        float4 sc0 = *(const float4*)&ssl[c0];
        float4 sc1 = *(const float4*)&ssl[c0 + 4];
        float4 sh0 = *(const float4*)&ssl[128 + c0];
        float4 sh1 = *(const float4*)&ssl[128 + c0 + 4];
        float scv[8] = {sc0.x, sc0.y, sc0.z, sc0.w, sc1.x, sc1.y, sc1.z, sc1.w};
        float shv[8] = {sh0.x, sh0.y, sh0.z, sh0.w, sh1.x, sh1.y, sh1.z, sh1.w};
        if (HAS_RES) {
            ushort4 rl = *(const ushort4*)(Rr + kc * 32);
            ushort4 rh = *(const ushort4*)(Rr + kc * 32 + 4);
            unsigned short rv[8] = {rl.x, rl.y, rl.z, rl.w, rh.x, rh.y, rh.z, rh.w};
#pragma unroll
            for (int j = 0; j < 8; j++) {
                float yy = fmaxf(bf2f(av[j]) * scv[j] + shv[j], 0.f) + bf2f(rv[j]);
                y[kc][j] = yy; sq += yy * yy;
            }
        } else {
#pragma unroll
            for (int j = 0; j < 8; j++) {
                float yy = fmaxf(bf2f(av[j]) * scv[j] + shv[j], 0.f);
                y[kc][j] = yy; sq += yy * yy;
            }
        }
    }
    sq += __shfl_xor(sq, 16, 64);
    sq += __shfl_xor(sq, 32, 64);
    float inv = 1.f / fmaxf(sqrtf(sq), L2_EPS);

    bf16x8 af[4];
#pragma unroll
    for (int kc = 0; kc < 4; kc++) {
        unsigned short t[8];
#pragma unroll
        for (int j = 0; j < 8; j++) t[j] = f2bf(y[kc][j] * inv);
        af[kc] = *(const bf16x8*)t;
        *(bf16x8*)&hbf_out[(size_t)rr * DD + q * 8 + kc * 32] = af[kc];
    }

    f32x4 acc[8];
#pragma unroll
    for (int cc = 0; cc < 8; cc++) acc[cc] = (f32x4){0.f, 0.f, 0.f, 0.f};
#pragma unroll
    for (int kc = 0; kc < 4; kc++)
#pragma unroll
        for (int cc = 0; cc < 8; cc++) {
            bf16x8 b = *(const bf16x8*)&Ws[(size_t)((kc * 8 + cc) * 64 + lane) * 8];
            acc[cc] = __builtin_amdgcn_mfma_f32_16x16x32_bf16(af[kc], b, acc[cc], 0, 0, 0);
        }

#pragma unroll
    for (int cc = 0; cc < 8; cc++)
#pragma unroll
        for (int i = 0; i < 4; i++) {
            int r = R0 + q * 4 + i;
            if (r < nrows) linb_out[(size_t)r * DD + cc * 16 + m] = f2bf(acc[cc][i]);
        }
}

// Fused output: h3 = l2norm(relu(bn(aggX)) + res);  out = h3 @ Wout + bout (fp32)
__global__ __launch_bounds__(256) void k_outfused(const unsigned short* __restrict__ aggX,
                                                  const float* __restrict__ stats,
                                                  const float* __restrict__ g,
                                                  const float* __restrict__ be, float inv_n,
                                                  const unsigned short* __restrict__ resb,
                                                  const unsigned short* __restrict__ wob,
                                                  const float* __restrict__ bout,
                                                  float* __restrict__ C, int nrows) {
    __shared__ __align__(16) unsigned short Ws[6144];
    __shared__ float ssl[256];
    const int tid = threadIdx.x;
    for (int i = tid; i < 768; i += 256)
        ((uint4*)Ws)[i] = ((const uint4*)wob)[i];
    if (tid < 128) {
        float sa = 0.f, sb = 0.f;
        for (int r = 0; r < NREP; r++) {
            sa += stats[r * 256 + tid];
            sb += stats[r * 256 + 128 + tid];
        }
        float mu = sa * inv_n;
        float var = sb * inv_n - mu * mu;
        float sc = g[tid] * rsqrtf(var + BN_EPS);
        ssl[tid] = sc;
        ssl[128 + tid] = be[tid] - mu * sc;
    }
    __syncthreads();

    const int wv = tid >> 6;
    const int lane = tid & 63;
    const int R0 = blockIdx.x * 64 + wv * 16;
    if (R0 >= nrows) return;
    const int m = lane & 15, q = lane >> 4;
    int rr = R0 + m; if (rr >= nrows) rr = nrows - 1;
    const unsigned short* Ar = aggX + (size_t)rr * DD + q * 8;
    const unsigned short* Rr = resb + (size_t)rr * DD + q * 8;

    float y[4][8];
    float sq = 0.f;
#pragma unroll
    for (int kc = 0; kc < 4; kc++) {
        ushort4 lo = *(const ushort4*)(Ar + kc * 32);
        ushort4 hi = *(const ushort4*)(Ar + kc * 32 + 4);
        ushort4 rl = *(const ushort4*)(Rr + kc * 32);
        ushort4 rh = *(const ushort4*)(Rr + kc * 32 + 4);
        unsigned short av[8] = {lo.x, lo.y, lo.z, lo.w, hi.x, hi.y, hi.z, hi.w};
        unsigned short rv[8] = {rl.x, rl.y, rl.z, rl.w, rh.x, rh.y, rh.z, rh.w};
        int c0 = kc * 32 + q * 8;
        float4 sc0 = *(const float4*)&ssl[c0];
        float4 sc1 = *(const float4*)&ssl[c0 + 4];
        float4 sh0 = *(const float4*)&ssl[128 + c0];
        float4 sh1 = *(const float4*)&ssl[128 + c0 + 4];
        float scv[8] = {sc0.x, sc0.y, sc0.z, sc0.w, sc1.x, sc1.y, sc1.z, sc1.w};
        float shv[8] = {sh0.x, sh0.y, sh0.z, sh0.w, sh1.x, sh1.y, sh1.z, sh1.w};
#pragma unroll
        for (int j = 0; j < 8; j++) {
            float yy = fmaxf(bf2f(av[j]) * scv[j] + shv[j], 0.f) + bf2f(rv[j]);
            y[kc][j] = yy; sq += yy * yy;
        }
    }
    sq += __shfl_xor(sq, 16, 64);
    sq += __shfl_xor(sq, 32, 64);
    float inv = 1.f / fmaxf(sqrtf(sq), L2_EPS);

    bf16x8 af[4];
#pragma unroll
    for (int kc = 0; kc < 4; kc++) {
        unsigned short t[8];
#pragma unroll
        for (int j = 0; j < 8; j++) t[j] = f2bf(y[kc][j] * inv);
        af[kc] = *(const bf16x8*)t;
    }

    f32x4 acc[3];
#pragma unroll
    for (int cc = 0; cc < 3; cc++) acc[cc] = (f32x4){0.f, 0.f, 0.f, 0.f};
#pragma unroll
    for (int kc = 0; kc < 4; kc++)
#pragma unroll
        for (int cc = 0; cc < 3; cc++) {
            bf16x8 b = *(const bf16x8*)&Ws[(size_t)((kc * 3 + cc) * 64 + lane) * 8];
            acc[cc] = __builtin_amdgcn_mfma_f32_16x16x32_bf16(af[kc], b, acc[cc], 0, 0, 0);
        }

#pragma unroll
    for (int cc = 0; cc < 3; cc++) {
        int col = cc * 16 + m;
        if (col < COUT) {
            float bb = bout[col];
#pragma unroll
            for (int i = 0; i < 4; i++) {
                int r = R0 + q * 4 + i;
                if (r < nrows) C[(size_t)r * COUT + col] = acc[cc][i] + bb;
            }
        }
    }
}

// ---------------- host ----------------

extern "C" void kernel_launch(void* const* d_in, const int* in_sizes, int n_in,
                              void* d_out, int out_size, void* d_ws, size_t ws_size,
                              hipStream_t stream) {
    const float* x    = (const float*)d_in[0];
    const int*   ei   = (const int*)d_in[1];
    const float* W1   = (const float*)d_in[2];
    const float* b1   = (const float*)d_in[3];
    const float* W2   = (const float*)d_in[4];
    const float* b2   = (const float*)d_in[5];
    const float* W3   = (const float*)d_in[6];
    const float* b3   = (const float*)d_in[7];
    const float* g1   = (const float*)d_in[8];
    const float* be1  = (const float*)d_in[9];
    const float* g2   = (const float*)d_in[10];
    const float* be2  = (const float*)d_in[11];
    const float* g3   = (const float*)d_in[12];
    const float* be3  = (const float*)d_in[13];
    const float* Wout = (const float*)d_in[14];
    const float* bout = (const float*)d_in[15];
    float* out = (float*)d_out;

    const int N = in_sizes[0] / DD;
    const int E = in_sizes[1] / 2;
    const int NNZ = E + N;
    const int SSTRIDE = NREP * 256;          // floats per layer's stats

    // workspace layout
    char* w = (char*)d_ws;
    unsigned short* linb = (unsigned short*)w; w += (size_t)N * DD * sizeof(unsigned short);
    unsigned short* aggA = (unsigned short*)w; w += (size_t)N * DD * sizeof(unsigned short);
    unsigned short* aggB = (unsigned short*)w; w += (size_t)N * DD * sizeof(unsigned short);
    unsigned short* hbf1 = (unsigned short*)w; w += (size_t)N * DD * sizeof(unsigned short);
    unsigned short* hbf2 = (unsigned short*)w; w += (size_t)N * DD * sizeof(unsigned short);
    unsigned short* wb   = (unsigned short*)w; w += 3 * 16384 * sizeof(unsigned short);
    unsigned short* wob  = (unsigned short*)w; w += 6144 * sizeof(unsigned short);
    int2* epair  = (int2*)w;                   w += (size_t)NNZ * sizeof(int2);
    int* pord    = (int*)w;                    w += (size_t)E * sizeof(int);
    int* deg     = (int*)w;                    w += (size_t)N * sizeof(int);
    int* row_ptr = (int*)w;                    w += (size_t)(N + 1) * sizeof(int);
    float* dinv  = (float*)w;                  w += (size_t)N * sizeof(float);
    int* bsum    = (int*)w;                    w += 512 * sizeof(int);
    int* boff    = (int*)w;                    w += 512 * sizeof(int);
    float* stats = (float*)w;                  w += 3 * (size_t)SSTRIDE * sizeof(float);

    const int NB = (N + 1 + 255) / 256;      // scan blocks

    // ---- CSR build + weight repack ----
    hipMemsetAsync(deg, 0, (size_t)N * sizeof(int), stream);
    k_wrepack_all<<<35, 256, 0, stream>>>(W1, W2, W3, Wout, wb, wob, stats);
    k_hist<<<(E + 255) / 256, 256, 0, stream>>>(ei, E, deg, pord);
    k_scan_a<<<NB, 256, 0, stream>>>(deg, row_ptr, bsum, dinv, N);
    k_scan_b<<<1, 512, 0, stream>>>(bsum, boff, NB);
    k_scan_c<<<(N + 1 + 255) / 256, 256, 0, stream>>>(row_ptr, boff, N + 1);
    k_fill<<<(NNZ + 255) / 256, 256, 0, stream>>>(ei, pord, E, N, row_ptr, dinv, epair);

    int gemmGrid = (N + 63) / 64;
    int aggGrid = (N + 7) / 8;               // one node per half-wave, no grid-stride
    float inv_n = 1.0f / (float)N;

    // ---- layer 1 ----
    k_gemm0<<<gemmGrid, 256, 0, stream>>>(x, wb, linb, N);
    k_aggs<<<aggGrid, 256, 0, stream>>>(linb, row_ptr, epair, dinv, b1, aggA, stats, N);
    // ---- layer 2 (post1 fused into gemm2) ----
    k_fused<false><<<gemmGrid, 256, 0, stream>>>(aggA, stats, g1, be1, inv_n,
                                                 nullptr, wb + 16384, hbf1, linb, N);
    k_aggs<<<aggGrid, 256, 0, stream>>>(linb, row_ptr, epair, dinv, b2, aggB,
                                        stats + SSTRIDE, N);
    // ---- layer 3 (post2 fused into gemm3) ----
    k_fused<true><<<gemmGrid, 256, 0, stream>>>(aggB, stats + SSTRIDE, g2, be2, inv_n,
                                                hbf1, wb + 32768, hbf2, linb, N);
    k_aggs<<<aggGrid, 256, 0, stream>>>(linb, row_ptr, epair, dinv, b3, aggA,
                                        stats + 2 * SSTRIDE, N);
    // ---- output (post3 fused into output GEMM) ----
    k_outfused<<<gemmGrid, 256, 0, stream>>>(aggA, stats + 2 * SSTRIDE, g3, be3, inv_n,
                                             hbf2, wob, bout, out, N);
}